// Round 3
// baseline (628.404 us; speedup 1.0000x reference)
//
#include <hip/hip_runtime.h>
#include <hip/hip_bf16.h>

typedef __bf16 bf16;
typedef __attribute__((ext_vector_type(8))) __bf16 bf16x8;
typedef __attribute__((ext_vector_type(4))) float f32x4;

#define E_EDGES 262144
#define MT 128   // rows per block

// Pre-pass: transpose + fp32->bf16 convert weights into workspace.
// W1 fp32 [384][512] -> W1t bf16 [512][384];  W2 fp32 [512][128] -> W2t bf16 [128][512]
__global__ void transpose_w(const float* __restrict__ W1, const float* __restrict__ W2,
                            bf16* __restrict__ W1t, bf16* __restrict__ W2t)
{
  int tid = blockIdx.x * 256 + threadIdx.x;
  if (tid < 512 * 384) {
    int n = tid / 384;
    int k = tid - n * 384;
    W1t[tid] = (bf16)W1[k * 512 + n];
  }
  if (tid < 128 * 512) {
    int n = tid >> 9;
    int k = tid & 511;
    W2t[tid] = (bf16)W2[k * 128 + n];
  }
}

__device__ __forceinline__ bf16x8 cvt8(const float* p) {
  f32x4 a = *(const f32x4*)p;
  f32x4 b = *(const f32x4*)(p + 4);
  bf16x8 r;
  r[0] = (bf16)a[0]; r[1] = (bf16)a[1]; r[2] = (bf16)a[2]; r[3] = (bf16)a[3];
  r[4] = (bf16)b[0]; r[5] = (bf16)b[1]; r[6] = (bf16)b[2]; r[7] = (bf16)b[3];
  return r;
}

// Fused: h = silu(concat(x_i,x_j,ea) @ W1 + b1); y = LN(h @ W2 + b2)*g + b + ea
__global__ __launch_bounds__(512, 4)
void fused_edge_mlp(const float* __restrict__ x_i,
                    const float* __restrict__ x_j,
                    const float* __restrict__ ea,
                    const bf16* __restrict__ W1t,
                    const float* __restrict__ b1,
                    const bf16* __restrict__ W2t,
                    const float* __restrict__ b2,
                    const float* __restrict__ gmm,
                    const float* __restrict__ bta,
                    float* __restrict__ out)
{
  __shared__ bf16 As[128 * 32];     // A staging tile (8KB)
  __shared__ bf16 Bs[128 * 32];     // W1t staging tile (8KB)
  __shared__ bf16 W2s[128 * 32];    // W2t staging tile (8KB)
  __shared__ bf16 H1s[128 * 136];   // h1 chunk [128][128] padded +8 (34.8KB)

  const int t    = threadIdx.x;
  const int w    = t >> 6;            // wave 0..7
  const int lane = t & 63;
  const int l15  = lane & 15;
  const int q    = lane >> 4;         // quad 0..3
  const int srow = t >> 2;            // staging row 0..127 (4 threads/row)
  const int sc8  = (t & 3) << 3;      // staging col 0,8,16,24
  const int wm   = w >> 2;            // phase-1 row half (64 rows)
  const int wn   = w & 3;             // phase-1 col quarter (32 cols)
  const long m0  = (long)blockIdx.x * MT;

  const f32x4 fzero = {0.f, 0.f, 0.f, 0.f};

  f32x4 acc2[8];                      // C2 [16 x 128] per wave (rows 16w..16w+15)
  #pragma unroll
  for (int i = 0; i < 8; ++i) acc2[i] = fzero;

  for (int nc = 0; nc < 4; ++nc) {
    f32x4 acc1[8];                    // C1 [64 x 32] per wave
    #pragma unroll
    for (int i = 0; i < 8; ++i) acc1[i] = fzero;

    // ---- GEMM1: C1 = A[128,384] @ W1t(nc*128.., :)^T, K-loop BK=32 ----
    for (int kk = 0; kk < 12; ++kk) {
      // global loads into registers first (overlaps barrier wait)
      const float* src = (kk < 4) ? x_i : (kk < 8) ? x_j : ea;
      bf16x8 av = cvt8(src + (m0 + srow) * 128 + ((kk & 3) << 5) + sc8);
      bf16x8 bv = *(const bf16x8*)(W1t + (long)(nc * 128 + srow) * 384 + (kk << 5) + sc8);

      __syncthreads();   // previous tile consumers done -> safe to overwrite
      *(bf16x8*)&As[srow * 32 + sc8] = av;
      *(bf16x8*)&Bs[srow * 32 + sc8] = bv;
      __syncthreads();   // staging visible to all

      bf16x8 af[4], bfr[2];
      #pragma unroll
      for (int mi = 0; mi < 4; ++mi)
        af[mi] = *(const bf16x8*)&As[(64 * wm + 16 * mi + l15) * 32 + 8 * q];
      #pragma unroll
      for (int ni = 0; ni < 2; ++ni)
        bfr[ni] = *(const bf16x8*)&Bs[(32 * wn + 16 * ni + l15) * 32 + 8 * q];
      #pragma unroll
      for (int mi = 0; mi < 4; ++mi)
        #pragma unroll
        for (int ni = 0; ni < 2; ++ni)
          acc1[mi * 2 + ni] = __builtin_amdgcn_mfma_f32_16x16x32_bf16(
              af[mi], bfr[ni], acc1[mi * 2 + ni], 0, 0, 0);
    }

    // ---- epilogue: bias + SiLU -> H1s (C/D layout -> row-major LDS) ----
    {
      float b1v[2];
      #pragma unroll
      for (int ni = 0; ni < 2; ++ni)
        b1v[ni] = b1[nc * 128 + 32 * wn + 16 * ni + l15];
      #pragma unroll
      for (int mi = 0; mi < 4; ++mi)
        #pragma unroll
        for (int ni = 0; ni < 2; ++ni)
          #pragma unroll
          for (int i = 0; i < 4; ++i) {
            float s = acc1[mi * 2 + ni][i] + b1v[ni];
            float h = s / (1.f + __expf(-s));
            H1s[(64 * wm + 16 * mi + 4 * q + i) * 136 + 32 * wn + 16 * ni + l15] = (bf16)h;
          }
    }

    // ---- GEMM2 partial: C2 += H1chunk[128,128] @ W2t(:, nc*128..)^T ----
    for (int s4 = 0; s4 < 4; ++s4) {
      bf16x8 wv = *(const bf16x8*)(W2t + (long)srow * 512 + nc * 128 + (s4 << 5) + sc8);

      __syncthreads();   // W2s consumers done; s4=0 also fences H1s writes
      *(bf16x8*)&W2s[srow * 32 + sc8] = wv;
      __syncthreads();

      bf16x8 a2 = *(const bf16x8*)&H1s[(16 * w + l15) * 136 + (s4 << 5) + 8 * q];
      #pragma unroll
      for (int ni = 0; ni < 8; ++ni) {
        bf16x8 b2f = *(const bf16x8*)&W2s[(16 * ni + l15) * 32 + 8 * q];
        acc2[ni] = __builtin_amdgcn_mfma_f32_16x16x32_bf16(a2, b2f, acc2[ni], 0, 0, 0);
      }
    }
  }

  // ---- LN + gamma/beta + residual; wave w owns rows [16w,16w+16) ----
  float b2v[8], gv[8], bv[8];
  #pragma unroll
  for (int ni = 0; ni < 8; ++ni) {
    int n = 16 * ni + l15;
    b2v[ni] = b2[n];
    gv[ni]  = gmm[n];
    bv[ni]  = bta[n];
  }
  #pragma unroll
  for (int ni = 0; ni < 8; ++ni)
    #pragma unroll
    for (int i = 0; i < 4; ++i)
      acc2[ni][i] += b2v[ni];

  #pragma unroll
  for (int i = 0; i < 4; ++i) {
    float s = 0.f, s2 = 0.f;
    #pragma unroll
    for (int ni = 0; ni < 8; ++ni) {
      float v = acc2[ni][i];
      s += v;
      s2 += v * v;
    }
    // reduce across the 16 lanes of this quad (row r=4q+i lives in one quad)
    #pragma unroll
    for (int off = 1; off <= 8; off <<= 1) {
      s  += __shfl_xor(s,  off, 64);
      s2 += __shfl_xor(s2, off, 64);
    }
    float mu   = s * (1.f / 128.f);
    float var  = fmaxf(s2 * (1.f / 128.f) - mu * mu, 0.f);
    float rstd = rsqrtf(var + 1e-5f);
    long  mg   = m0 + 16 * w + 4 * q + i;
    #pragma unroll
    for (int ni = 0; ni < 8; ++ni) {
      int n = 16 * ni + l15;
      float o = (acc2[ni][i] - mu) * rstd * gv[ni] + bv[ni] + ea[mg * 128 + n];
      out[mg * 128 + n] = o;
    }
  }
}

extern "C" void kernel_launch(void* const* d_in, const int* in_sizes, int n_in,
                              void* d_out, int out_size, void* d_ws, size_t ws_size,
                              hipStream_t stream)
{
  const float* x_i = (const float*)d_in[0];
  const float* x_j = (const float*)d_in[1];
  const float* ea  = (const float*)d_in[2];
  const float* W1  = (const float*)d_in[3];
  const float* b1  = (const float*)d_in[4];
  const float* W2  = (const float*)d_in[5];
  const float* b2  = (const float*)d_in[6];
  const float* gm  = (const float*)d_in[7];
  const float* bt  = (const float*)d_in[8];
  float* outp = (float*)d_out;
  bf16* W1t = (bf16*)d_ws;           // 512*384 bf16
  bf16* W2t = W1t + 512 * 384;       // 128*512 bf16

  hipLaunchKernelGGL(transpose_w, dim3(768), dim3(256), 0, stream, W1, W2, W1t, W2t);
  hipLaunchKernelGGL(fused_edge_mlp, dim3(E_EDGES / MT), dim3(512), 0, stream,
                     x_i, x_j, ea, W1t, b1, W2t, b2, gm, bt, outp);
}